// Round 6
// baseline (238.808 us; speedup 1.0000x reference)
//
#include <hip/hip_runtime.h>
#include <cstdint>

typedef unsigned short u16;
typedef __bf16 bf16x8 __attribute__((ext_vector_type(8)));
typedef float f32x4 __attribute__((ext_vector_type(4)));
typedef unsigned int u32x4 __attribute__((ext_vector_type(4)));
typedef unsigned short u16x4 __attribute__((ext_vector_type(4)));
typedef unsigned short u16x8 __attribute__((ext_vector_type(8)));

__device__ __forceinline__ float bf2f(u16 h) {
  union { unsigned int u; float f; } v; v.u = ((unsigned int)h) << 16; return v.f;
}
__device__ __forceinline__ u16 f2bf(float f) {
  union { float f; unsigned int u; } v; v.f = f;
  unsigned int u = v.u;
  return (u16)((u + 0x7FFFu + ((u >> 16) & 1u)) >> 16);  // RNE, finite inputs
}

__device__ __forceinline__ void ld_lds16(const void* g, void* l) {
  __builtin_amdgcn_global_load_lds(
      (const __attribute__((address_space(1))) unsigned int*)g,
      (__attribute__((address_space(3))) unsigned int*)l, 16, 0, 0);
}

// ---------------------------------------------------------------------------
// GEMM1: S = (H * K^T)/32 as bf16 in 4-row-grouped layout:
//   S_u16[ (row>>2)*16384 + col*4 + (row&3) ]
// (chunk g = rows 4g..4g+3 occupies the same 32KB byte range as row-major.)
// 128x128 tiles, grid 1024 flat, XCD region 16 rows x 8 cols. Epilogue is
// direct coalesced 8B stores straight from the MFMA C-layout (r=consecutive
// rows per lane) — no LDS transpose, no extra barriers.
// ---------------------------------------------------------------------------
__global__ __launch_bounds__(256) void gemm1_kernel(
    const u16* __restrict__ A, const u16* __restrict__ B,
    u16* __restrict__ S, int ldA, int ldB)
{
  __shared__ u16 As[128 * 64];   // 16 KB
  __shared__ u16 Bs[128 * 64];   // 16 KB

  const int tid  = threadIdx.x;
  const int lane = tid & 63;
  const int w    = tid >> 6;
  const int wr   = w >> 1;
  const int wc   = w & 1;
  const int quad = lane >> 4;
  const int cIn  = lane & 15;

  const int flat = blockIdx.x;
  const int xcd  = flat & 7;
  const int i    = flat >> 3;
  const int rowBlk = ((xcd >> 2) * 16 + (i & 15)) * 128;
  const int colBlk = ((xcd & 3) * 8 + (i >> 4)) * 128;

  const int lrow   = lane >> 3;
  const int gchunk = (lane & 7) ^ lrow;

  f32x4 acc[4][4];
  #pragma unroll
  for (int a = 0; a < 4; ++a)
    #pragma unroll
    for (int b = 0; b < 4; ++b) acc[a][b] = {0.f, 0.f, 0.f, 0.f};

  for (int k0 = 0; k0 < 1024; k0 += 64) {
    #pragma unroll
    for (int t = 0; t < 4; ++t) {
      int rg = w * 4 + t;
      const u16* ga = A + (size_t)(rowBlk + rg * 8 + lrow) * ldA + k0 + gchunk * 8;
      const u16* gb = B + (size_t)(colBlk + rg * 8 + lrow) * ldB + k0 + gchunk * 8;
      ld_lds16(ga, &As[rg * 512]);
      ld_lds16(gb, &Bs[rg * 512]);
    }
    __syncthreads();

    #pragma unroll
    for (int ks = 0; ks < 2; ++ks) {
      bf16x8 af[4], bfr[4];
      #pragma unroll
      for (int mi = 0; mi < 4; ++mi) {
        int row = wr * 64 + mi * 16 + cIn;
        int ch  = (ks * 4 + quad) ^ (row & 7);
        af[mi]  = *(const bf16x8*)&As[row * 64 + ch * 8];
      }
      #pragma unroll
      for (int ni = 0; ni < 4; ++ni) {
        int row = wc * 64 + ni * 16 + cIn;
        int ch  = (ks * 4 + quad) ^ (row & 7);
        bfr[ni] = *(const bf16x8*)&Bs[row * 64 + ch * 8];
      }
      #pragma unroll
      for (int mi = 0; mi < 4; ++mi)
        #pragma unroll
        for (int ni = 0; ni < 4; ++ni)
          acc[mi][ni] = __builtin_amdgcn_mfma_f32_16x16x32_bf16(
              af[mi], bfr[ni], acc[mi][ni], 0, 0, 0);
    }
    __syncthreads();
  }

  // Epilogue: grouped-layout stores. Lane's 4 acc regs = 4 consecutive rows
  // of one column -> one u16x4 (8B) store; 16 lanes (cIn) = 128B contiguous.
  const float scale = 0.03125f;  // 1/sqrt(1024)
  #pragma unroll
  for (int mi = 0; mi < 4; ++mi) {
    int grp = (rowBlk >> 2) + wr * 16 + mi * 4 + quad;
    #pragma unroll
    for (int ni = 0; ni < 4; ++ni) {
      int col = colBlk + wc * 64 + ni * 16 + cIn;
      u16x4 v;
      #pragma unroll
      for (int r = 0; r < 4; ++r) v[r] = f2bf(acc[mi][ni][r] * scale);
      *(u16x4*)&S[((size_t)grp * 4096 + col) * 4] = v;
    }
  }
}

// ---------------------------------------------------------------------------
// GEMM2: out = (P2 @ Vt^T) / L2. 64x128 tiles, BK=128 (two 64-halves),
// full K=4096, grid 512 flat, XCD region 8x8. P2 is row-major bf16.
// ---------------------------------------------------------------------------
__global__ __launch_bounds__(256) void gemm2_kernel(
    const u16* __restrict__ A, const u16* __restrict__ B,
    float* __restrict__ Out, const float* __restrict__ L2,
    int ldA, int ldB, int ldC)
{
  __shared__ u16 As[2 * 64 * 64];    // 16 KB
  __shared__ u16 Bs[2 * 128 * 64];   // 32 KB

  const int tid  = threadIdx.x;
  const int lane = tid & 63;
  const int w    = tid >> 6;
  const int wrow = w >> 1;
  const int wcol = w & 1;
  const int quad = lane >> 4;
  const int cIn  = lane & 15;

  const int flat = blockIdx.x;
  const int xcd  = flat & 7;
  const int i    = flat >> 3;
  const int rowBlk = (xcd * 8 + (i & 7)) * 64;
  const int colBlk = (i >> 3) * 128;

  const int lrow   = lane >> 3;
  const int gchunk = (lane & 7) ^ lrow;

  f32x4 acc[2][4];
  #pragma unroll
  for (int a = 0; a < 2; ++a)
    #pragma unroll
    for (int b = 0; b < 4; ++b) acc[a][b] = {0.f, 0.f, 0.f, 0.f};

  for (int k0 = 0; k0 < 4096; k0 += 128) {
    #pragma unroll
    for (int h = 0; h < 2; ++h) {
      int kk = k0 + h * 64;
      #pragma unroll
      for (int t = 0; t < 2; ++t) {
        int rg = w * 2 + t;
        const u16* ga = A + (size_t)(rowBlk + rg * 8 + lrow) * ldA + kk + gchunk * 8;
        ld_lds16(ga, &As[h * 4096 + rg * 512]);
      }
      #pragma unroll
      for (int t = 0; t < 4; ++t) {
        int rg = w * 4 + t;
        const u16* gb = B + (size_t)(colBlk + rg * 8 + lrow) * ldB + kk + gchunk * 8;
        ld_lds16(gb, &Bs[h * 8192 + rg * 512]);
      }
    }
    __syncthreads();

    #pragma unroll
    for (int h = 0; h < 2; ++h) {
      #pragma unroll
      for (int ks = 0; ks < 2; ++ks) {
        bf16x8 af[2], bfr[4];
        #pragma unroll
        for (int mi = 0; mi < 2; ++mi) {
          int row = wrow * 32 + mi * 16 + cIn;
          int ch  = (ks * 4 + quad) ^ (row & 7);
          af[mi]  = *(const bf16x8*)&As[h * 4096 + row * 64 + ch * 8];
        }
        #pragma unroll
        for (int ni = 0; ni < 4; ++ni) {
          int row = wcol * 64 + ni * 16 + cIn;
          int ch  = (ks * 4 + quad) ^ (row & 7);
          bfr[ni] = *(const bf16x8*)&Bs[h * 8192 + row * 64 + ch * 8];
        }
        #pragma unroll
        for (int mi = 0; mi < 2; ++mi)
          #pragma unroll
          for (int ni = 0; ni < 4; ++ni)
            acc[mi][ni] = __builtin_amdgcn_mfma_f32_16x16x32_bf16(
                af[mi], bfr[ni], acc[mi][ni], 0, 0, 0);
      }
    }
    __syncthreads();
  }

  #pragma unroll
  for (int mi = 0; mi < 2; ++mi) {
    #pragma unroll
    for (int r = 0; r < 4; ++r) {
      int row   = rowBlk + wrow * 32 + mi * 16 + quad * 4 + r;
      float inv = 1.0f / L2[row];
      #pragma unroll
      for (int ni = 0; ni < 4; ++ni) {
        int col = colBlk + wcol * 64 + ni * 16 + cIn;
        __builtin_nontemporal_store(acc[mi][ni][r] * inv,
                                    &Out[(size_t)row * ldC + col]);
      }
    }
  }
}

// Fused prep: [0,8192) cvt H/K, [8192,10240) transpose V (64x32 tiles,
// 16B coalesced writes).
__global__ __launch_bounds__(256) void prep_kernel(
    const float* __restrict__ H, const float* __restrict__ Kin,
    const float* __restrict__ V, u16* __restrict__ Hb, u16* __restrict__ Kb,
    u16* __restrict__ Vt)
{
  int b = blockIdx.x;
  if (b < 8192) {
    const float* src = (b < 4096) ? H : Kin;
    u16* dst = (b < 4096) ? Hb : Kb;
    int i = (b & 4095) * 256 + threadIdx.x;
    float4 v = ((const float4*)src)[i];
    ushort4 o;
    o.x = f2bf(v.x); o.y = f2bf(v.y); o.z = f2bf(v.z); o.w = f2bf(v.w);
    ((ushort4*)dst)[i] = o;
  } else {
    __shared__ u16 tile[32 * 72];   // [D-col][M-row], stride 72 (16B-aligned)
    b -= 8192;
    int r0 = (b >> 5) * 64;         // 64 M-rows per block (4096/64 = 64)
    int c0 = (b & 31) * 32;         // 32 D-cols per block (1024/32 = 32)
    int row = threadIdx.x >> 2;     // 0..63
    int f4  = threadIdx.x & 3;
    #pragma unroll
    for (int j = 0; j < 2; ++j) {
      float4 v = *(const float4*)&V[(size_t)(r0 + row) * 1024 + c0 + (f4 * 2 + j) * 4];
      int cc = f4 * 8 + j * 4;
      tile[(cc + 0) * 72 + row] = f2bf(v.x);
      tile[(cc + 1) * 72 + row] = f2bf(v.y);
      tile[(cc + 2) * 72 + row] = f2bf(v.z);
      tile[(cc + 3) * 72 + row] = f2bf(v.w);
    }
    __syncthreads();
    int cc2   = threadIdx.x >> 3;   // 0..31
    int chunk = threadIdx.x & 7;    // 0..7
    u16x8 o = *(const u16x8*)&tile[cc2 * 72 + chunk * 8];
    *(u16x8*)&Vt[(size_t)(c0 + cc2) * 4096 + r0 + chunk * 8] = o;
  }
}

// softmax2: one block per 4-row group. Reads S (grouped layout, coalesced),
// computes L1 per row, p = exp(exp(s)/L1 * mask), writes P2 row-major
// IN PLACE (same 32KB chunk), row sums -> L2. All HBM loads hoisted.
__global__ __launch_bounds__(256) void softmax2_kernel(
    u16* __restrict__ S, const float* __restrict__ mask,
    float* __restrict__ L2)
{
  const int g = blockIdx.x;            // 0..1023
  const int t = threadIdx.x;
  u16* chunk = S + (size_t)g * 16384;  // 32 KB

  // load: 16 cols x 4 rows, grouped = col*4 + r  (t covers cols 16t..16t+15)
  u16 sv[64];
  #pragma unroll
  for (int q = 0; q < 8; ++q)
    *(u32x4*)(sv + q * 8) = *(const u32x4*)(chunk + t * 64 + q * 8);
  float mv[4][16];
  #pragma unroll
  for (int r = 0; r < 4; ++r)
    #pragma unroll
    for (int q = 0; q < 4; ++q)
      *(f32x4*)(&mv[r][q * 4]) =
          *(const f32x4*)(mask + (size_t)(g * 4 + r) * 4096 + t * 16 + q * 4);

  float e[4][16];
  float p1[4] = {0.f, 0.f, 0.f, 0.f};
  #pragma unroll
  for (int c = 0; c < 16; ++c)
    #pragma unroll
    for (int r = 0; r < 4; ++r) {
      e[r][c] = __expf(bf2f(sv[c * 4 + r]));
      p1[r] += e[r][c];
    }

  __shared__ float wred1[4][4], wred2[4][4];
  #pragma unroll
  for (int m = 1; m < 64; m <<= 1)
    #pragma unroll
    for (int r = 0; r < 4; ++r) p1[r] += __shfl_xor(p1[r], m, 64);
  if ((t & 63) == 0)
    #pragma unroll
    for (int r = 0; r < 4; ++r) wred1[t >> 6][r] = p1[r];
  __syncthreads();   // also guarantees all S reads done before in-place writes

  float inv1[4];
  #pragma unroll
  for (int r = 0; r < 4; ++r)
    inv1[r] = 1.0f / (wred1[0][r] + wred1[1][r] + wred1[2][r] + wred1[3][r]);

  float s2[4] = {0.f, 0.f, 0.f, 0.f};
  #pragma unroll
  for (int r = 0; r < 4; ++r) {
    u16 pv[16];
    #pragma unroll
    for (int c = 0; c < 16; ++c) {
      float p = __expf(e[r][c] * inv1[r] * mv[r][c]);
      s2[r] += p;
      pv[c] = f2bf(p);
    }
    // row-major in-place write: row g*4+r, cols 16t..16t+15 (32B)
    u16* dst = S + (size_t)(g * 4 + r) * 4096 + t * 16;
    *(u32x4*)(dst)     = *(const u32x4*)(pv);
    *(u32x4*)(dst + 8) = *(const u32x4*)(pv + 8);
  }

  #pragma unroll
  for (int m = 1; m < 64; m <<= 1)
    #pragma unroll
    for (int r = 0; r < 4; ++r) s2[r] += __shfl_xor(s2[r], m, 64);
  if ((t & 63) == 0)
    #pragma unroll
    for (int r = 0; r < 4; ++r) wred2[t >> 6][r] = s2[r];
  __syncthreads();
  if (t < 4)
    L2[g * 4 + t] = wred2[0][t] + wred2[1][t] + wred2[2][t] + wred2[3][t];
}

extern "C" void kernel_launch(void* const* d_in, const int* in_sizes, int n_in,
                              void* d_out, int out_size, void* d_ws, size_t ws_size,
                              hipStream_t stream) {
  const float* H    = (const float*)d_in[0];
  const float* Kin  = (const float*)d_in[1];
  const float* V    = (const float*)d_in[2];
  const float* mask = (const float*)d_in[3];
  float* out = (float*)d_out;

  const int N = 4096, M = 4096, D = 1024;

  char* ws = (char*)d_ws;
  u16*   Hb = (u16*)(ws);
  u16*   Kb = (u16*)(ws + (8ull << 20));
  u16*   Vt = (u16*)(ws + (16ull << 20));
  u16*   S  = (u16*)(ws + (24ull << 20));
  float* L2 = (float*)(ws + (56ull << 20));

  prep_kernel<<<dim3(10240), dim3(256), 0, stream>>>(H, Kin, V, Hb, Kb, Vt);

  gemm1_kernel<<<dim3(1024), dim3(256), 0, stream>>>(Hb, Kb, S, D, D);

  softmax2_kernel<<<dim3(N / 4), dim3(256), 0, stream>>>(S, mask, L2);

  gemm2_kernel<<<dim3(512), dim3(256), 0, stream>>>(S, Vt, out, L2, M, M, D);
}